// Round 2
// baseline (428.241 us; speedup 1.0000x reference)
//
#include <hip/hip_runtime.h>
#include <cstdint>
#include <cstddef>

#define T_TOK 4096
#define HIDDIM 2560
#define NH 8
#define NKV 4
#define HD 256
#define SEQ 2048
#define NBATCH 2
#define WIN 1024
#define NQKV 4096          // (8+2*4)*256
#define QSCALE 0.0625f     // 256^-0.5

typedef unsigned short u16;
typedef __attribute__((ext_vector_type(8))) __bf16 bf16x8;
typedef __attribute__((ext_vector_type(8))) u16 u16x8;
typedef __attribute__((ext_vector_type(4))) float f32x4;

__device__ __forceinline__ u16 f2bf(float f) {
  union { float f; uint32_t u; } x{f};
  uint32_t r = x.u + 0x7FFFu + ((x.u >> 16) & 1u);
  return (u16)(r >> 16);
}
__device__ __forceinline__ float bf2f(u16 h) {
  union { uint32_t u; float f; } x{((uint32_t)h) << 16};
  return x.f;
}
__device__ __forceinline__ void gload_lds16(const void* g, void* l) {
  __builtin_amdgcn_global_load_lds((const __attribute__((address_space(1))) unsigned int*)g,
                                   (__attribute__((address_space(3))) unsigned int*)l, 16, 0, 0);
}

// ---------------- fp32 -> bf16 convert ----------------
__global__ void cvt_bf16(const float* __restrict__ in, u16* __restrict__ out, int n8) {
  int i = blockIdx.x * 256 + threadIdx.x;
  if (i >= n8) return;
  const f32x4* p = (const f32x4*)(in + (size_t)i * 8);
  f32x4 a = p[0], b = p[1];
  u16 o[8];
  o[0] = f2bf(a[0]); o[1] = f2bf(a[1]); o[2] = f2bf(a[2]); o[3] = f2bf(a[3]);
  o[4] = f2bf(b[0]); o[5] = f2bf(b[1]); o[6] = f2bf(b[2]); o[7] = f2bf(b[3]);
  *(u16x8*)(out + (size_t)i * 8) = *(const u16x8*)o;
}

// ---------------- GEMM: C[M,N] = A[M,K] * Bt[N,K]^T  (m97-style) ----------------
template <int OUTBF16>
__global__ __launch_bounds__(256, 2) void gemm_bt(const u16* __restrict__ A,
                                                  const u16* __restrict__ Bt,
                                                  void* __restrict__ Cp,
                                                  int M, int N, int K) {
  __shared__ u16 As[128 * 32];
  __shared__ u16 Bs[128 * 32];
  const int t = threadIdx.x, lane = t & 63, w = t >> 6;
  const int wr = w >> 1, wc = w & 1, hi = lane >> 4, lo = lane & 15;
  const int m0 = blockIdx.y * 128, n0 = blockIdx.x * 128;
  f32x4 acc[4][4] = {};
  for (int k0 = 0; k0 < K; k0 += 32) {
#pragma unroll
    for (int it = 0; it < 2; ++it) {
      int c = t + it * 256;  // chunk id; row=c>>2, col=(c&3)*8 ; lds byte = c*16
      gload_lds16(A + (size_t)(m0 + (c >> 2)) * K + k0 + (c & 3) * 8,
                  (char*)As + w * 1024 + it * 4096);
      gload_lds16(Bt + (size_t)(n0 + (c >> 2)) * K + k0 + (c & 3) * 8,
                  (char*)Bs + w * 1024 + it * 4096);
    }
    asm volatile("s_waitcnt vmcnt(0)" ::: "memory");
    __syncthreads();
    bf16x8 a[4], b[4];
#pragma unroll
    for (int mi = 0; mi < 4; ++mi) a[mi] = *(const bf16x8*)&As[(wr * 64 + mi * 16 + lo) * 32 + hi * 8];
#pragma unroll
    for (int ni = 0; ni < 4; ++ni) b[ni] = *(const bf16x8*)&Bs[(wc * 64 + ni * 16 + lo) * 32 + hi * 8];
#pragma unroll
    for (int mi = 0; mi < 4; ++mi)
#pragma unroll
      for (int ni = 0; ni < 4; ++ni)
        acc[mi][ni] = __builtin_amdgcn_mfma_f32_16x16x32_bf16(a[mi], b[ni], acc[mi][ni], 0, 0, 0);
    __syncthreads();
  }
#pragma unroll
  for (int mi = 0; mi < 4; ++mi) {
#pragma unroll
    for (int ni = 0; ni < 4; ++ni) {
      int row = m0 + wr * 64 + mi * 16 + hi * 4;
      int col = n0 + wc * 64 + ni * 16 + lo;
#pragma unroll
      for (int r = 0; r < 4; ++r) {
        if (OUTBF16)
          ((u16*)Cp)[(size_t)(row + r) * N + col] = f2bf(acc[mi][ni][r]);
        else
          ((float*)Cp)[(size_t)(row + r) * N + col] = acc[mi][ni][r];
      }
    }
  }
}

// ---------------- fused RMSNorm + RoPE for q,k (scale folded into q) ----------------
__global__ void norm_rope(const u16* __restrict__ qkv, const float* __restrict__ cosb,
                          const float* __restrict__ sinb, const float* __restrict__ qw,
                          const float* __restrict__ kw, u16* __restrict__ qn,
                          u16* __restrict__ kn) {
  int gw = blockIdx.x * 4 + (threadIdx.x >> 6);  // wave id over T_TOK*12
  int lane = threadIdx.x & 63;
  int t = gw / 12, hh = gw % 12;  // 0..7 q heads, 8..11 k heads
  const u16* x = qkv + (size_t)t * NQKV + hh * HD;
  int d = lane * 2;
  float x1a = bf2f(x[d]), x1b = bf2f(x[d + 1]);
  float x2a = bf2f(x[d + 128]), x2b = bf2f(x[d + 129]);
  float ss = x1a * x1a + x1b * x1b + x2a * x2a + x2b * x2b;
#pragma unroll
  for (int off = 1; off < 64; off <<= 1) ss += __shfl_xor(ss, off, 64);
  float inv = rsqrtf(ss * (1.0f / 256.0f) + 1e-6f);
  const float* wp = (hh < 8) ? qw : kw;
  float c0 = cosb[t * 128 + d], c1 = cosb[t * 128 + d + 1];
  float s0 = sinb[t * 128 + d], s1 = sinb[t * 128 + d + 1];
  float sc = (hh < 8) ? QSCALE : 1.0f;
  float y1a = x1a * inv * wp[d], y1b = x1b * inv * wp[d + 1];
  float y2a = x2a * inv * wp[d + 128], y2b = x2b * inv * wp[d + 129];
  float o1a = (y1a * c0 - y2a * s0) * sc, o1b = (y1b * c1 - y2b * s1) * sc;
  float o2a = (y2a * c0 + y1a * s0) * sc, o2b = (y2b * c1 + y1b * s1) * sc;
  u16* o = (hh < 8) ? (qn + ((size_t)t * 8 + hh) * HD) : (kn + ((size_t)t * 4 + (hh - 8)) * HD);
  ushort2 lo2, hi2;
  lo2.x = f2bf(o1a); lo2.y = f2bf(o1b);
  hi2.x = f2bf(o2a); hi2.y = f2bf(o2b);
  *(ushort2*)&o[d] = lo2;
  *(ushort2*)&o[d + 128] = hi2;
}

// ---------------- V transpose: qkv v-slice -> vt[b][kv][d][s] ----------------
__global__ void vtransp(const u16* __restrict__ qkv, u16* __restrict__ vt) {
  const int b = blockIdx.y >> 2, kv = blockIdx.y & 3;
  const int s0 = blockIdx.x * 64;
  const int t = threadIdx.x;
  __shared__ u16 tile[64 * 64];
  for (int d0 = 0; d0 < 256; d0 += 64) {
#pragma unroll
    for (int it = 0; it < 2; ++it) {
      int c = t + it * 256;
      int sr = c >> 3, dc = (c & 7) * 8;
      bf16x8 v = *(const bf16x8*)&qkv[(size_t)(b * SEQ + s0 + sr) * NQKV + 3072 + kv * HD + d0 + dc];
      *(bf16x8*)((char*)tile + ((sr * 128 + dc * 2) ^ ((sr & 7) << 4))) = v;
    }
    __syncthreads();
#pragma unroll
    for (int it = 0; it < 2; ++it) {
      int c = t + it * 256;
      int dr = c >> 3, sc0 = (c & 7) * 8;
      union { u16 a[8]; bf16x8 v; } u;
#pragma unroll
      for (int j = 0; j < 8; ++j) {
        int s = sc0 + j;
        u.a[j] = *(const u16*)((char*)tile + ((s * 128 + dr * 2) ^ ((s & 7) << 4)));
      }
      *(bf16x8*)&vt[((size_t)(b * 4 + kv) * 256 + d0 + dr) * SEQ + s0 + sc0] = u.v;
    }
    __syncthreads();
  }
}

// ---------------- flash attention, sliding window, GQA ----------------
__global__ __launch_bounds__(256, 2) void attn_fwd(const u16* __restrict__ qn,
                                                   const u16* __restrict__ kn,
                                                   const u16* __restrict__ vt,
                                                   u16* __restrict__ aout) {
  const int qt = blockIdx.x * 64, h = blockIdx.y, b = blockIdx.z;
  const int kvh = h >> 1;
  const int t = threadIdx.x, lane = t & 63, w = t >> 6, hi = lane >> 4, lo = lane & 15;
  __shared__ u16 Ks[32 * 256];   // [k][d], swizzled: byte ^ ((k&7)<<4)
  __shared__ u16 Vs[256 * 32];   // [d][k], swizzled: byte ^ ((d&7)<<4)
  __shared__ u16 Ps[4][16 * 32]; // per-wave P [q][k], swizzled: byte ^ ((q&7)<<4)
  bf16x8 qf[8];
  const int qrow = qt + w * 16 + lo;
#pragma unroll
  for (int dd = 0; dd < 8; ++dd)
    qf[dd] = *(const bf16x8*)&qn[((size_t)(b * SEQ + qrow) * 8 + h) * HD + dd * 32 + hi * 8];
  f32x4 oacc[16] = {};
  float mrow[4] = {-3e38f, -3e38f, -3e38f, -3e38f};
  float lrow[4] = {0.f, 0.f, 0.f, 0.f};
  const int kstart = qt >= WIN ? qt - WIN : 0;
  const int irow = qt + w * 16 + hi * 4;
  for (int kt = kstart; kt < qt + 64; kt += 32) {
    // stage K tile 32x256
#pragma unroll
    for (int it = 0; it < 4; ++it) {
      int c = t + it * 256;
      int kr = c >> 5, dc = (c & 31) * 8;
      bf16x8 val = *(const bf16x8*)&kn[((size_t)(b * SEQ + kt + kr) * 4 + kvh) * HD + dc];
      *(bf16x8*)((char*)Ks + ((kr * 512 + dc * 2) ^ ((kr & 7) << 4))) = val;
    }
    // stage V^T tile 256x32
#pragma unroll
    for (int it = 0; it < 4; ++it) {
      int c = t + it * 256;
      int dr = c >> 2, kc = (c & 3) * 8;
      bf16x8 val = *(const bf16x8*)&vt[((size_t)(b * 4 + kvh) * 256 + dr) * SEQ + kt + kc];
      *(bf16x8*)((char*)Vs + ((dr * 64 + kc * 2) ^ ((dr & 7) << 4))) = val;
    }
    __syncthreads();
    // QK^T : S[q][k] ; q = hi*4+r, k = lo (per 16-key subtile)
    f32x4 sacc[2];
#pragma unroll
    for (int kk = 0; kk < 2; ++kk) {
      f32x4 sa = {0.f, 0.f, 0.f, 0.f};
#pragma unroll
      for (int dd = 0; dd < 8; ++dd) {
        int krow = kk * 16 + lo;
        bf16x8 kf = *(const bf16x8*)((char*)Ks + ((krow * 512 + (dd * 32 + hi * 8) * 2) ^ ((krow & 7) << 4)));
        sa = __builtin_amdgcn_mfma_f32_16x16x32_bf16(qf[dd], kf, sa, 0, 0, 0);
      }
      sacc[kk] = sa;
    }
    // mask + online softmax
    float pe[2][4];
    float tmax[4] = {-3e38f, -3e38f, -3e38f, -3e38f};
#pragma unroll
    for (int kk = 0; kk < 2; ++kk)
#pragma unroll
      for (int r = 0; r < 4; ++r) {
        int i = irow + r, j = kt + kk * 16 + lo;
        bool ok = (j <= i) && (i - j < WIN);
        float sv = ok ? sacc[kk][r] : -3e38f;
        sacc[kk][r] = sv;
        tmax[r] = fmaxf(tmax[r], sv);
      }
#pragma unroll
    for (int off = 1; off < 16; off <<= 1)
#pragma unroll
      for (int r = 0; r < 4; ++r) tmax[r] = fmaxf(tmax[r], __shfl_xor(tmax[r], off, 64));
    float scl[4], tsum[4];
#pragma unroll
    for (int r = 0; r < 4; ++r) {
      float mnew = fmaxf(mrow[r], tmax[r]);
      scl[r] = __expf(mrow[r] - mnew);
      mrow[r] = mnew;
      tsum[r] = 0.f;
    }
#pragma unroll
    for (int kk = 0; kk < 2; ++kk)
#pragma unroll
      for (int r = 0; r < 4; ++r) {
        float sv = sacc[kk][r];
        float p = (sv <= -1e37f) ? 0.f : __expf(sv - mrow[r]);
        pe[kk][r] = p;
        tsum[r] += p;
      }
#pragma unroll
    for (int off = 1; off < 16; off <<= 1)
#pragma unroll
      for (int r = 0; r < 4; ++r) tsum[r] += __shfl_xor(tsum[r], off, 64);
#pragma unroll
    for (int r = 0; r < 4; ++r) lrow[r] = lrow[r] * scl[r] + tsum[r];
#pragma unroll
    for (int dt = 0; dt < 16; ++dt)
#pragma unroll
      for (int r = 0; r < 4; ++r) oacc[dt][r] *= scl[r];
    // write P (bf16) to per-wave LDS, [q][k] swizzled
#pragma unroll
    for (int kk = 0; kk < 2; ++kk)
#pragma unroll
      for (int r = 0; r < 4; ++r) {
        int q = hi * 4 + r, cc = kk * 16 + lo;
        *(u16*)((char*)&Ps[w][0] + ((q * 64 + cc * 2) ^ ((q & 7) << 4))) = f2bf(pe[kk][r]);
      }
    // PV: A = P rows (q=lo), B = V (k rows, d cols)
    bf16x8 pf = *(const bf16x8*)((char*)&Ps[w][0] + ((lo * 64 + hi * 16) ^ ((lo & 7) << 4)));
#pragma unroll
    for (int dt = 0; dt < 16; ++dt) {
      int d = dt * 16 + lo;
      bf16x8 vf = *(const bf16x8*)((char*)Vs + ((d * 64 + hi * 16) ^ ((d & 7) << 4)));
      oacc[dt] = __builtin_amdgcn_mfma_f32_16x16x32_bf16(pf, vf, oacc[dt], 0, 0, 0);
    }
    __syncthreads();
  }
  // epilogue: out[t][h*256+d] = oacc / l
#pragma unroll
  for (int dt = 0; dt < 16; ++dt)
#pragma unroll
    for (int r = 0; r < 4; ++r) {
      int i = irow + r;
      aout[(size_t)(b * SEQ + i) * 2048 + h * HD + dt * 16 + lo] = f2bf(oacc[dt][r] / lrow[r]);
    }
}

extern "C" void kernel_launch(void* const* d_in, const int* in_sizes, int n_in,
                              void* d_out, int out_size, void* d_ws, size_t ws_size,
                              hipStream_t stream) {
  const float* hs = (const float*)d_in[0];
  const float* cosb = (const float*)d_in[1];
  const float* sinb = (const float*)d_in[2];
  const float* wqkv = (const float*)d_in[3];
  const float* qw = (const float*)d_in[4];
  const float* kw = (const float*)d_in[5];
  const float* wo = (const float*)d_in[6];
  char* ws = (char*)d_ws;
  // lifetimes allow overlap: A reused by attn-out, B reused by qn
  u16* hs_b = (u16*)(ws);                   // 20.97 MB   [dead after GEMM1]
  u16* wqkv_b = (u16*)(ws + 20971520);      // 20.97 MB   [dead after GEMM1]
  u16* wo_b = (u16*)(ws + 41943040);        // 10.49 MB
  u16* qkv_b = (u16*)(ws + 52428800);       // 33.55 MB
  u16* kn = (u16*)(ws + 85983232);          // 8.39 MB
  u16* vt = (u16*)(ws + 94371840);          // 8.39 MB   (total 102.76 MB)
  u16* qn = wqkv_b;                         // reuse
  u16* attn = hs_b;                         // reuse

  cvt_bf16<<<5120, 256, 0, stream>>>(hs, hs_b, 1310720);
  cvt_bf16<<<5120, 256, 0, stream>>>(wqkv, wqkv_b, 1310720);
  cvt_bf16<<<2560, 256, 0, stream>>>(wo, wo_b, 655360);
  gemm_bt<1><<<dim3(32, 32), 256, 0, stream>>>(hs_b, wqkv_b, qkv_b, 4096, 4096, 2560);
  norm_rope<<<12288, 256, 0, stream>>>(qkv_b, cosb, sinb, qw, kw, qn, kn);
  vtransp<<<dim3(32, 8), 256, 0, stream>>>(qkv_b, vt);
  attn_fwd<<<dim3(32, 8, 2), 256, 0, stream>>>(qn, kn, vt, attn);
  gemm_bt<0><<<dim3(20, 32), 256, 0, stream>>>(attn, wo_b, d_out, 4096, 2560, 2048);
}

// Round 7
// 423.898 us; speedup vs baseline: 1.0102x; 1.0102x over previous
//
#include <hip/hip_runtime.h>
#include <cstdint>
#include <cstddef>

#define T_TOK 4096
#define HIDDIM 2560
#define NH 8
#define NKV 4
#define HD 256
#define SEQ 2048
#define NBATCH 2
#define WIN 1024
#define NQKV 4096          // (8+2*4)*256
#define QSCALE 0.0625f     // 256^-0.5

typedef unsigned short u16;
typedef __attribute__((ext_vector_type(8))) __bf16 bf16x8;
typedef __attribute__((ext_vector_type(8))) u16 u16x8;
typedef __attribute__((ext_vector_type(4))) float f32x4;

__device__ __forceinline__ u16 f2bf(float f) {
  union { float f; uint32_t u; } x{f};
  uint32_t r = x.u + 0x7FFFu + ((x.u >> 16) & 1u);
  return (u16)(r >> 16);
}
__device__ __forceinline__ float bf2f(u16 h) {
  union { uint32_t u; float f; } x{((uint32_t)h) << 16};
  return x.f;
}
__device__ __forceinline__ void gload_lds16(const void* g, void* l) {
  __builtin_amdgcn_global_load_lds((const __attribute__((address_space(1))) unsigned int*)g,
                                   (__attribute__((address_space(3))) unsigned int*)l, 16, 0, 0);
}
template <int N>
__device__ __forceinline__ void vmcnt_wait() {
  if constexpr (N >= 8) asm volatile("s_waitcnt vmcnt(8)" ::: "memory");
  else if constexpr (N == 6) asm volatile("s_waitcnt vmcnt(6)" ::: "memory");
  else if constexpr (N == 4) asm volatile("s_waitcnt vmcnt(4)" ::: "memory");
  else if constexpr (N == 3) asm volatile("s_waitcnt vmcnt(3)" ::: "memory");
  else asm volatile("s_waitcnt vmcnt(0)" ::: "memory");
}

// ---------------- fp32 -> bf16 convert ----------------
__global__ void cvt_bf16(const float* __restrict__ in, u16* __restrict__ out, int n8) {
  int i = blockIdx.x * 256 + threadIdx.x;
  if (i >= n8) return;
  const f32x4* p = (const f32x4*)(in + (size_t)i * 8);
  f32x4 a = p[0], b = p[1];
  u16 o[8];
  o[0] = f2bf(a[0]); o[1] = f2bf(a[1]); o[2] = f2bf(a[2]); o[3] = f2bf(a[3]);
  o[4] = f2bf(b[0]); o[5] = f2bf(b[1]); o[6] = f2bf(b[2]); o[7] = f2bf(b[3]);
  *(u16x8*)(out + (size_t)i * 8) = *(const u16x8*)o;
}

// ---------------- GEMM 256x{256|128} tile, BK=32, 4-buffer counted-vmcnt pipeline
// C[M,N] = A[M,K] * Bt[N,K]^T. 8 waves (2Mx4N), per-wave output 128 x BN/4.
// LDS swizzle: frag (row r, kchunk hi) at byte (r*64+hi*16)^((r&7)<<4) (bijective;
// inverse applied to global source so global_load_lds dest stays linear).
template <int M, int N, int K, int BN, int OUTBF16>
__global__ __launch_bounds__(512, 2) void gemm256(const u16* __restrict__ A,
                                                  const u16* __restrict__ Bt,
                                                  void* __restrict__ Cp) {
  constexpr int NT = K / 32;           // K-tiles
  constexpr int BCH = BN * 4;          // B 16B-chunks per tile (A = 1024)
  constexpr int LPT = (1024 + BCH) / 512;  // gloads per thread per tile (4 or 3)
  constexpr int NREP = BN / 64;        // b-frags per wave
  constexpr int BUFB = 16384 + BN * 64;    // bytes per buffer (A + B)
  __shared__ char smem[4 * BUFB];

  const int tid = threadIdx.x, lane = tid & 63, w = tid >> 6;
  const int wr = w >> 2, wc = w & 3, hi = lane >> 4, lo = lane & 15;
  const int hi16 = hi * 16;
  // XCD-aware bijective swizzle (total%8==0 for both instantiations)
  constexpr int TOT = (M / 256) * (N / BN);
  const int bid = blockIdx.x;
  const int wg = (bid & 7) * (TOT / 8) + (bid >> 3);
  const int m0 = (wg / (N / BN)) * 256;
  const int n0 = (wg % (N / BN)) * BN;

  f32x4 acc[8][NREP] = {};

  auto stage = [&](int tt, int bb) {
    const int k0 = tt * 32;
    char* base = smem + bb * BUFB;
#pragma unroll
    for (int it = 0; it < 2; ++it) {           // A: 1024 chunks
      int c = tid + it * 512;
      int r = (c >> 2) ^ ((c >> 4) & 1);
      int h = (c & 3) ^ (r & 3);
      gload_lds16(A + (size_t)(m0 + r) * K + k0 + h * 8, base + c * 16);
    }
#pragma unroll
    for (int it = 0; it < BCH / 512; ++it) {   // B: BCH chunks
      int c = tid + it * 512;
      int r = (c >> 2) ^ ((c >> 4) & 1);
      int h = (c & 3) ^ (r & 3);
      gload_lds16(Bt + (size_t)(n0 + r) * K + k0 + h * 8, base + 16384 + c * 16);
    }
  };
  auto body = [&](int bb) {
    char* base = smem + bb * BUFB;
    bf16x8 a[8], b[NREP];
#pragma unroll
    for (int mi = 0; mi < 8; ++mi) {
      int r = wr * 128 + mi * 16 + lo;
      a[mi] = *(const bf16x8*)(base + ((r * 64 + hi16) ^ ((r & 7) << 4)));
    }
#pragma unroll
    for (int ni = 0; ni < NREP; ++ni) {
      int r = wc * (BN / 4) + ni * 16 + lo;
      b[ni] = *(const bf16x8*)(base + 16384 + ((r * 64 + hi16) ^ ((r & 7) << 4)));
    }
    __builtin_amdgcn_s_setprio(1);
#pragma unroll
    for (int mi = 0; mi < 8; ++mi)
#pragma unroll
      for (int ni = 0; ni < NREP; ++ni)
        acc[mi][ni] = __builtin_amdgcn_mfma_f32_16x16x32_bf16(a[mi], b[ni], acc[mi][ni], 0, 0, 0);
    __builtin_amdgcn_s_setprio(0);
  };

  // prologue: 3 tiles in flight, tile0 complete
  stage(0, 0); stage(1, 1); stage(2, 2);
  vmcnt_wait<2 * LPT>();
  __builtin_amdgcn_s_barrier();
  int t = 0;
  for (; t < NT - 3; ++t) {
    stage(t + 3, (t + 3) & 3);
    body(t & 3);
    vmcnt_wait<2 * LPT>();       // tile t+1 complete; t+2,t+3 stay in flight
    __builtin_amdgcn_s_barrier();
  }
  body(t & 3); vmcnt_wait<LPT>(); __builtin_amdgcn_s_barrier(); ++t;   // NT-3
  body(t & 3); vmcnt_wait<0>();   __builtin_amdgcn_s_barrier(); ++t;   // NT-2
  body(t & 3);                                                         // NT-1

#pragma unroll
  for (int mi = 0; mi < 8; ++mi)
#pragma unroll
    for (int ni = 0; ni < NREP; ++ni) {
      int row = m0 + wr * 128 + mi * 16 + hi * 4;
      int col = n0 + wc * (BN / 4) + ni * 16 + lo;
#pragma unroll
      for (int r = 0; r < 4; ++r) {
        if (OUTBF16)
          ((u16*)Cp)[(size_t)(row + r) * N + col] = f2bf(acc[mi][ni][r]);
        else
          ((float*)Cp)[(size_t)(row + r) * N + col] = acc[mi][ni][r];
      }
    }
}

// ---------------- fused RMSNorm + RoPE for q,k (scale folded into q) ----------------
__global__ void norm_rope(const u16* __restrict__ qkv, const float* __restrict__ cosb,
                          const float* __restrict__ sinb, const float* __restrict__ qw,
                          const float* __restrict__ kw, u16* __restrict__ qn,
                          u16* __restrict__ kn) {
  int gw = blockIdx.x * 4 + (threadIdx.x >> 6);  // wave id over T_TOK*12
  int lane = threadIdx.x & 63;
  int t = gw / 12, hh = gw % 12;  // 0..7 q heads, 8..11 k heads
  const u16* x = qkv + (size_t)t * NQKV + hh * HD;
  int d = lane * 2;
  float x1a = bf2f(x[d]), x1b = bf2f(x[d + 1]);
  float x2a = bf2f(x[d + 128]), x2b = bf2f(x[d + 129]);
  float ss = x1a * x1a + x1b * x1b + x2a * x2a + x2b * x2b;
#pragma unroll
  for (int off = 1; off < 64; off <<= 1) ss += __shfl_xor(ss, off, 64);
  float inv = rsqrtf(ss * (1.0f / 256.0f) + 1e-6f);
  const float* wp = (hh < 8) ? qw : kw;
  float c0 = cosb[t * 128 + d], c1 = cosb[t * 128 + d + 1];
  float s0 = sinb[t * 128 + d], s1 = sinb[t * 128 + d + 1];
  float sc = (hh < 8) ? QSCALE : 1.0f;
  float y1a = x1a * inv * wp[d], y1b = x1b * inv * wp[d + 1];
  float y2a = x2a * inv * wp[d + 128], y2b = x2b * inv * wp[d + 129];
  float o1a = (y1a * c0 - y2a * s0) * sc, o1b = (y1b * c1 - y2b * s1) * sc;
  float o2a = (y2a * c0 + y1a * s0) * sc, o2b = (y2b * c1 + y1b * s1) * sc;
  u16* o = (hh < 8) ? (qn + ((size_t)t * 8 + hh) * HD) : (kn + ((size_t)t * 4 + (hh - 8)) * HD);
  ushort2 lo2, hi2;
  lo2.x = f2bf(o1a); lo2.y = f2bf(o1b);
  hi2.x = f2bf(o2a); hi2.y = f2bf(o2b);
  *(ushort2*)&o[d] = lo2;
  *(ushort2*)&o[d + 128] = hi2;
}

// ---------------- V transpose: qkv v-slice -> vt[b][kv][d][s] ----------------
__global__ void vtransp(const u16* __restrict__ qkv, u16* __restrict__ vt) {
  const int b = blockIdx.y >> 2, kv = blockIdx.y & 3;
  const int s0 = blockIdx.x * 64;
  const int t = threadIdx.x;
  __shared__ u16 tile[64 * 64];
  for (int d0 = 0; d0 < 256; d0 += 64) {
#pragma unroll
    for (int it = 0; it < 2; ++it) {
      int c = t + it * 256;
      int sr = c >> 3, dc = (c & 7) * 8;
      bf16x8 v = *(const bf16x8*)&qkv[(size_t)(b * SEQ + s0 + sr) * NQKV + 3072 + kv * HD + d0 + dc];
      *(bf16x8*)((char*)tile + ((sr * 128 + dc * 2) ^ ((sr & 7) << 4))) = v;
    }
    __syncthreads();
#pragma unroll
    for (int it = 0; it < 2; ++it) {
      int c = t + it * 256;
      int dr = c >> 3, sc0 = (c & 7) * 8;
      union { u16 a[8]; bf16x8 v; } u;
#pragma unroll
      for (int j = 0; j < 8; ++j) {
        int s = sc0 + j;
        u.a[j] = *(const u16*)((char*)tile + ((s * 128 + dr * 2) ^ ((s & 7) << 4)));
      }
      *(bf16x8*)&vt[((size_t)(b * 4 + kv) * 256 + d0 + dr) * SEQ + s0 + sc0] = u.v;
    }
    __syncthreads();
  }
}

// ---------------- flash attention, sliding window, GQA ----------------
__global__ __launch_bounds__(256, 2) void attn_fwd(const u16* __restrict__ qn,
                                                   const u16* __restrict__ kn,
                                                   const u16* __restrict__ vt,
                                                   u16* __restrict__ aout) {
  const int qt = blockIdx.x * 64, h = blockIdx.y, b = blockIdx.z;
  const int kvh = h >> 1;
  const int t = threadIdx.x, lane = t & 63, w = t >> 6, hi = lane >> 4, lo = lane & 15;
  __shared__ u16 Ks[32 * 256];   // [k][d], swizzled: byte ^ ((k&7)<<4)
  __shared__ u16 Vs[256 * 32];   // [d][k], swizzled: byte ^ ((d&7)<<4)
  __shared__ u16 Ps[4][16 * 32]; // per-wave P [q][k], swizzled: byte ^ ((q&7)<<4)
  bf16x8 qf[8];
  const int qrow = qt + w * 16 + lo;
#pragma unroll
  for (int dd = 0; dd < 8; ++dd)
    qf[dd] = *(const bf16x8*)&qn[((size_t)(b * SEQ + qrow) * 8 + h) * HD + dd * 32 + hi * 8];
  f32x4 oacc[16] = {};
  float mrow[4] = {-3e38f, -3e38f, -3e38f, -3e38f};
  float lrow[4] = {0.f, 0.f, 0.f, 0.f};
  const int kstart = qt >= WIN ? qt - WIN : 0;
  const int irow = qt + w * 16 + hi * 4;
  for (int kt = kstart; kt < qt + 64; kt += 32) {
    // stage K tile 32x256
#pragma unroll
    for (int it = 0; it < 4; ++it) {
      int c = t + it * 256;
      int kr = c >> 5, dc = (c & 31) * 8;
      bf16x8 val = *(const bf16x8*)&kn[((size_t)(b * SEQ + kt + kr) * 4 + kvh) * HD + dc];
      *(bf16x8*)((char*)Ks + ((kr * 512 + dc * 2) ^ ((kr & 7) << 4))) = val;
    }
    // stage V^T tile 256x32
#pragma unroll
    for (int it = 0; it < 4; ++it) {
      int c = t + it * 256;
      int dr = c >> 2, kc = (c & 3) * 8;
      bf16x8 val = *(const bf16x8*)&vt[((size_t)(b * 4 + kvh) * 256 + dr) * SEQ + kt + kc];
      *(bf16x8*)((char*)Vs + ((dr * 64 + kc * 2) ^ ((dr & 7) << 4))) = val;
    }
    __syncthreads();
    // QK^T : S[q][k] ; q = hi*4+r, k = lo (per 16-key subtile)
    f32x4 sacc[2];
#pragma unroll
    for (int kk = 0; kk < 2; ++kk) {
      f32x4 sa = {0.f, 0.f, 0.f, 0.f};
#pragma unroll
      for (int dd = 0; dd < 8; ++dd) {
        int krow = kk * 16 + lo;
        bf16x8 kf = *(const bf16x8*)((char*)Ks + ((krow * 512 + (dd * 32 + hi * 8) * 2) ^ ((krow & 7) << 4)));
        sa = __builtin_amdgcn_mfma_f32_16x16x32_bf16(qf[dd], kf, sa, 0, 0, 0);
      }
      sacc[kk] = sa;
    }
    // mask + online softmax
    float pe[2][4];
    float tmax[4] = {-3e38f, -3e38f, -3e38f, -3e38f};
#pragma unroll
    for (int kk = 0; kk < 2; ++kk)
#pragma unroll
      for (int r = 0; r < 4; ++r) {
        int i = irow + r, j = kt + kk * 16 + lo;
        bool ok = (j <= i) && (i - j < WIN);
        float sv = ok ? sacc[kk][r] : -3e38f;
        sacc[kk][r] = sv;
        tmax[r] = fmaxf(tmax[r], sv);
      }
#pragma unroll
    for (int off = 1; off < 16; off <<= 1)
#pragma unroll
      for (int r = 0; r < 4; ++r) tmax[r] = fmaxf(tmax[r], __shfl_xor(tmax[r], off, 64));
    float scl[4], tsum[4];
#pragma unroll
    for (int r = 0; r < 4; ++r) {
      float mnew = fmaxf(mrow[r], tmax[r]);
      scl[r] = __expf(mrow[r] - mnew);
      mrow[r] = mnew;
      tsum[r] = 0.f;
    }
#pragma unroll
    for (int kk = 0; kk < 2; ++kk)
#pragma unroll
      for (int r = 0; r < 4; ++r) {
        float sv = sacc[kk][r];
        float p = (sv <= -1e37f) ? 0.f : __expf(sv - mrow[r]);
        pe[kk][r] = p;
        tsum[r] += p;
      }
#pragma unroll
    for (int off = 1; off < 16; off <<= 1)
#pragma unroll
      for (int r = 0; r < 4; ++r) tsum[r] += __shfl_xor(tsum[r], off, 64);
#pragma unroll
    for (int r = 0; r < 4; ++r) lrow[r] = lrow[r] * scl[r] + tsum[r];
#pragma unroll
    for (int dt = 0; dt < 16; ++dt)
#pragma unroll
      for (int r = 0; r < 4; ++r) oacc[dt][r] *= scl[r];
    // write P (bf16) to per-wave LDS, [q][k] swizzled
#pragma unroll
    for (int kk = 0; kk < 2; ++kk)
#pragma unroll
      for (int r = 0; r < 4; ++r) {
        int q = hi * 4 + r, cc = kk * 16 + lo;
        *(u16*)((char*)&Ps[w][0] + ((q * 64 + cc * 2) ^ ((q & 7) << 4))) = f2bf(pe[kk][r]);
      }
    // PV: A = P rows (q=lo), B = V (k rows, d cols)
    bf16x8 pf = *(const bf16x8*)((char*)&Ps[w][0] + ((lo * 64 + hi * 16) ^ ((lo & 7) << 4)));
#pragma unroll
    for (int dt = 0; dt < 16; ++dt) {
      int d = dt * 16 + lo;
      bf16x8 vf = *(const bf16x8*)((char*)Vs + ((d * 64 + hi * 16) ^ ((d & 7) << 4)));
      oacc[dt] = __builtin_amdgcn_mfma_f32_16x16x32_bf16(pf, vf, oacc[dt], 0, 0, 0);
    }
    __syncthreads();
  }
  // epilogue: out[t][h*256+d] = oacc / l
#pragma unroll
  for (int dt = 0; dt < 16; ++dt)
#pragma unroll
    for (int r = 0; r < 4; ++r) {
      int i = irow + r;
      aout[(size_t)(b * SEQ + i) * 2048 + h * HD + dt * 16 + lo] = f2bf(oacc[dt][r] / lrow[r]);
    }
}

extern "C" void kernel_launch(void* const* d_in, const int* in_sizes, int n_in,
                              void* d_out, int out_size, void* d_ws, size_t ws_size,
                              hipStream_t stream) {
  const float* hs = (const float*)d_in[0];
  const float* cosb = (const float*)d_in[1];
  const float* sinb = (const float*)d_in[2];
  const float* wqkv = (const float*)d_in[3];
  const float* qw = (const float*)d_in[4];
  const float* kw = (const float*)d_in[5];
  const float* wo = (const float*)d_in[6];
  char* ws = (char*)d_ws;
  u16* hs_b = (u16*)(ws);                   // 20.97 MB   [dead after GEMM1]
  u16* wqkv_b = (u16*)(ws + 20971520);      // 20.97 MB   [dead after GEMM1]
  u16* wo_b = (u16*)(ws + 41943040);        // 10.49 MB
  u16* qkv_b = (u16*)(ws + 52428800);       // 33.55 MB
  u16* kn = (u16*)(ws + 85983232);          // 8.39 MB
  u16* vt = (u16*)(ws + 94371840);          // 8.39 MB   (total 102.76 MB)
  u16* qn = wqkv_b;                         // reuse
  u16* attn = hs_b;                         // reuse

  cvt_bf16<<<5120, 256, 0, stream>>>(hs, hs_b, 1310720);
  cvt_bf16<<<5120, 256, 0, stream>>>(wqkv, wqkv_b, 1310720);
  cvt_bf16<<<2560, 256, 0, stream>>>(wo, wo_b, 655360);
  gemm256<4096, 4096, 2560, 256, 1><<<256, 512, 0, stream>>>(hs_b, wqkv_b, qkv_b);
  norm_rope<<<12288, 256, 0, stream>>>(qkv_b, cosb, sinb, qw, kw, qn, kn);
  vtransp<<<dim3(32, 8), 256, 0, stream>>>(qkv_b, vt);
  attn_fwd<<<dim3(32, 8, 2), 256, 0, stream>>>(qn, kn, vt, attn);
  gemm256<4096, 2560, 2048, 128, 0><<<320, 512, 0, stream>>>(attn, wo_b, d_out);
}